// Round 4
// baseline (227.492 us; speedup 1.0000x reference)
//
#include <hip/hip_runtime.h>
#include <hip/hip_cooperative_groups.h>

namespace cg = cooperative_groups;

// Problem constants: x [B=16, C=96, H=256, W=256] fp32, STRIDE=2, P_NORM=2.
// out [16, 96, 128, 128] fp32.
#define B  16
#define C  96
#define H  256
#define W  256
#define HO 128
#define WO 128

#define F4_PER_ROW   (W / 4)                 // 64 float4 per input row
#define F4_PER_BATCH (C * H * F4_PER_ROW)    // 1,572,864
#define OUT_F4       (B * C * HO * (WO / 4)) // 6,291,456
#define GX   64                              // blocks per batch (phase A)
#define BLK  256
#define NBLK (GX * B)                        // 1024 total blocks

typedef float nfloat4 __attribute__((ext_vector_type(4)));  // native vec for nontemporal store

// d_ws: partial[(b*4 + p)*GX + gx] -> 16*4*64 floats = 16 KB (fully
// overwritten every call; no zeroing needed, no atomics anywhere).

// Single fused cooperative kernel:
//   A: per-(batch,phase) sum of squares -> partial[]      (reads 403 MB)
//   grid.sync()
//   B: every block redundantly computes the 16 argmaxes (identical,
//      deterministic in all blocks -> no second sync needed)
//   C: gather winning phase -> out                        (reads 201 MB,
//      writes 100 MB nontemporally to avoid evicting input from L3)
__global__ __launch_bounds__(BLK, 4)
void aps_fused(const float4* __restrict__ in, float4* __restrict__ out,
               float* __restrict__ partial) {
    __shared__ float sm[4][4];
    __shared__ int   sm_idx[B];
    const int wave = threadIdx.x >> 6, lane = threadIdx.x & 63;

    // ---- Phase A: norms ----
    {
        const int b = blockIdx.y;
        const float4* base = in + (size_t)b * F4_PER_BATCH;
        float a00 = 0.f, a01 = 0.f, a10 = 0.f, a11 = 0.f; // [h&1][w&1]
        const int stride = GX * BLK;                       // 16384
        // 96 float4s per thread = 24 iterations of x4 unroll.
        // stride/64 = 256 (even) -> h-parity identical across unrolled loads
        // and wave-uniform (rows are 64 float4s).
        for (int i = blockIdx.x * BLK + threadIdx.x; i < F4_PER_BATCH; i += 4 * stride) {
            float4 v0 = base[i];
            float4 v1 = base[i + stride];
            float4 v2 = base[i + 2 * stride];
            float4 v3 = base[i + 3 * stride];
            float e = v0.x * v0.x + v0.z * v0.z + v1.x * v1.x + v1.z * v1.z
                    + v2.x * v2.x + v2.z * v2.z + v3.x * v3.x + v3.z * v3.z;
            float o = v0.y * v0.y + v0.w * v0.w + v1.y * v1.y + v1.w * v1.w
                    + v2.y * v2.y + v2.w * v2.w + v3.y * v3.y + v3.w * v3.w;
            if ((i >> 6) & 1) { a10 += e; a11 += o; }      // wave-uniform
            else              { a00 += e; a01 += o; }
        }
        #pragma unroll
        for (int off = 32; off; off >>= 1) {
            a00 += __shfl_down(a00, off);
            a01 += __shfl_down(a01, off);
            a10 += __shfl_down(a10, off);
            a11 += __shfl_down(a11, off);
        }
        if (lane == 0) {
            sm[wave][0] = a00; sm[wave][1] = a01; sm[wave][2] = a10; sm[wave][3] = a11;
        }
        __syncthreads();
        if (threadIdx.x < 4) {                              // one store per phase
            const int p = threadIdx.x;
            float s = sm[0][p] + sm[1][p] + sm[2][p] + sm[3][p];
            partial[(b * 4 + p) * GX + blockIdx.x] = s;
        }
    }

    cg::this_grid().sync();

    // ---- Phase B: every block computes all 16 argmaxes into LDS ----
    // wave w handles batches 4w..4w+3; lane l reduces partial[...*GX + l].
    // Deterministic fixed-order reduction, identical in every block.
    {
        #pragma unroll
        for (int k = 0; k < 4; ++k) {
            const int bb = wave * 4 + k;
            float s[4];
            #pragma unroll
            for (int p = 0; p < 4; ++p) {
                float v = partial[(bb * 4 + p) * GX + lane];
                #pragma unroll
                for (int off = 32; off; off >>= 1) v += __shfl_down(v, off);
                s[p] = v;
            }
            if (lane == 0) {
                int best = 0; float bm = s[0];   // strict > = first-max (jnp)
                if (s[1] > bm) { bm = s[1]; best = 1; }
                if (s[2] > bm) { bm = s[2]; best = 2; }
                if (s[3] > bm) { bm = s[3]; best = 3; }
                sm_idx[bb] = best;
            }
        }
        __syncthreads();
    }

    // ---- Phase C: gather ----
    // One output float4 per thread-iteration; two contiguous float4 input
    // loads cover cols 8t+j..8t+6+j. bc (= o>>12) is wave-uniform.
    {
        const int flat = blockIdx.y * GX + blockIdx.x;
        for (int o = flat * BLK + threadIdx.x; o < OUT_F4; o += NBLK * BLK) {
            int t  = o & 31;          // float4 index within output row
            int hp = (o >> 5) & 127;  // output row h'
            int bc = o >> 12;         // b*C + c
            int b  = bc / C;
            int phase = sm_idx[b];
            int i = phase >> 1, j = phase & 1;
            const float4* row = in + ((size_t)bc * H + (2 * hp + i)) * F4_PER_ROW;
            float4 a  = row[2 * t];
            float4 c4 = row[2 * t + 1];
            nfloat4 r;
            r.x = j ? a.y  : a.x;
            r.y = j ? a.w  : a.z;
            r.z = j ? c4.y : c4.x;
            r.w = j ? c4.w : c4.z;
            __builtin_nontemporal_store(r, (nfloat4*)&out[o]);
        }
    }
}

extern "C" void kernel_launch(void* const* d_in, const int* in_sizes, int n_in,
                              void* d_out, int out_size, void* d_ws, size_t ws_size,
                              hipStream_t stream) {
    const float4* in = (const float4*)d_in[0];
    float4* out = (float4*)d_out;
    float* partial = (float*)d_ws;   // 16 KB

    void* args[] = {(void*)&in, (void*)&out, (void*)&partial};
    (void)hipLaunchCooperativeKernel((const void*)aps_fused, dim3(GX, B), dim3(BLK),
                                     args, 0, stream);
}

// Round 5
// 132.253 us; speedup vs baseline: 1.7201x; 1.7201x over previous
//
#include <hip/hip_runtime.h>

// Problem constants: x [B=16, C=96, H=256, W=256] fp32, STRIDE=2, P_NORM=2.
// out [16, 96, 128, 128] fp32.
#define B  16
#define C  96
#define H  256
#define W  256
#define HO 128
#define WO 128

#define F4_PER_ROW   (W / 4)                 // 64 float4 per input row
#define F4_PER_BATCH (C * H * F4_PER_ROW)    // 1,572,864
#define OUT_F4       (B * C * HO * (WO / 4)) // 6,291,456
#define GX    256                            // norms blocks per batch
#define CHUNK (F4_PER_BATCH / GX)            // 6144 f4 = 96 rows per block
#define GG    4096                           // gather blocks
#define OPT   6                              // output f4 per thread (gather)

// d_ws: partial[(b*4 + p)*GX + gx] -> 16*4*256 floats = 64 KB.
// Fully overwritten every call; no atomics; no zeroing needed.

// Pass 1: per-(batch,phase) sum of squares.
// Block bx owns a contiguous 96-row chunk of batch b. Each wave's 64 lanes
// cover exactly one row (rows are 64 f4) -> h-parity = wave&1 (uniform).
// 8 independent load slots (stride 4 rows) x 3 iterations (stride 32 rows)
// keep 8 global loads in flight per wave.
__global__ void aps_norms(const float4* __restrict__ in, float* __restrict__ partial) {
    const int b = blockIdx.y, bx = blockIdx.x, tid = threadIdx.x;
    const int wave = tid >> 6, lane = tid & 63;
    const float4* base = in + (size_t)b * F4_PER_BATCH + (size_t)bx * CHUNK;
    float ae0 = 0.f, ae1 = 0.f, ao0 = 0.f, ao1 = 0.f;  // split chains for ILP
    #pragma unroll
    for (int k = 0; k < 3; ++k) {
        const float4* p = base + tid + k * 2048;
        float4 v0 = p[0 * 256];
        float4 v1 = p[1 * 256];
        float4 v2 = p[2 * 256];
        float4 v3 = p[3 * 256];
        float4 v4 = p[4 * 256];
        float4 v5 = p[5 * 256];
        float4 v6 = p[6 * 256];
        float4 v7 = p[7 * 256];
        ae0 += v0.x * v0.x + v0.z * v0.z + v1.x * v1.x + v1.z * v1.z
             + v2.x * v2.x + v2.z * v2.z + v3.x * v3.x + v3.z * v3.z;
        ae1 += v4.x * v4.x + v4.z * v4.z + v5.x * v5.x + v5.z * v5.z
             + v6.x * v6.x + v6.z * v6.z + v7.x * v7.x + v7.z * v7.z;
        ao0 += v0.y * v0.y + v0.w * v0.w + v1.y * v1.y + v1.w * v1.w
             + v2.y * v2.y + v2.w * v2.w + v3.y * v3.y + v3.w * v3.w;
        ao1 += v4.y * v4.y + v4.w * v4.w + v5.y * v5.y + v5.w * v5.w
             + v6.y * v6.y + v6.w * v6.w + v7.y * v7.y + v7.w * v7.w;
    }
    float ae = ae0 + ae1, ao = ao0 + ao1;
    #pragma unroll
    for (int off = 32; off; off >>= 1) {
        ae += __shfl_down(ae, off);
        ao += __shfl_down(ao, off);
    }
    __shared__ float sm[4][2];                    // [wave][w-parity component]
    if (lane == 0) { sm[wave][0] = ae; sm[wave][1] = ao; }
    __syncthreads();
    if (tid < 4) {                                // phase p = (h&1)*2 + (w&1)
        const int p = tid, i = p >> 1, j = p & 1;
        // waves whose (wave&1)==i are waves i and i+2
        partial[(b * 4 + p) * GX + bx] = sm[i][j] + sm[i + 2][j];
    }
}

// Pass 2: fused select+gather. Every block redundantly computes the argmax
// for ITS batch from the 4x256 partials (L2-resident, ~4 KB), then gathers.
// Fixed-order deterministic reduction; strict > = first-max (jnp.argmax).
__global__ void aps_select_gather(const float4* __restrict__ in,
                                  const float* __restrict__ partial,
                                  float4* __restrict__ out) {
    const int tid = threadIdx.x;
    const int wave = tid >> 6, lane = tid & 63;
    const int b = blockIdx.x >> 8;               // 256 blocks per batch
    __shared__ float smp[4];
    {
        const float* pp = partial + (b * 4 + wave) * GX;   // wave = phase
        float v = pp[lane] + pp[lane + 64] + pp[lane + 128] + pp[lane + 192];
        #pragma unroll
        for (int off = 32; off; off >>= 1) v += __shfl_down(v, off);
        if (lane == 0) smp[wave] = v;
    }
    __syncthreads();
    const float n0 = smp[0], n1 = smp[1], n2 = smp[2], n3 = smp[3];
    int best = 0; float bm = n0;
    if (n1 > bm) { bm = n1; best = 1; }
    if (n2 > bm) { bm = n2; best = 2; }
    if (n3 > bm) { bm = n3; best = 3; }
    const int i = best >> 1, j = best & 1;

    // 6 outputs per thread, fully unrolled -> 12 independent loads in flight.
    // out[b,c,hp,4t..4t+3] = x[b,c,2hp+i, 8t+j..8t+6+j step 2]
    const int obase = blockIdx.x * (256 * OPT) + tid;
    #pragma unroll
    for (int k = 0; k < OPT; ++k) {
        const int o  = obase + k * 256;
        const int t  = o & 31;                   // f4 index within output row
        const int hp = (o >> 5) & 127;           // output row h'
        const int bc = o >> 12;                  // b*C + c
        const float4* row = in + ((size_t)bc * H + (2 * hp + i)) * F4_PER_ROW;
        const float4 a  = row[2 * t];
        const float4 c4 = row[2 * t + 1];
        float4 r;
        r.x = j ? a.y  : a.x;
        r.y = j ? a.w  : a.z;
        r.z = j ? c4.y : c4.x;
        r.w = j ? c4.w : c4.z;
        out[o] = r;
    }
}

extern "C" void kernel_launch(void* const* d_in, const int* in_sizes, int n_in,
                              void* d_out, int out_size, void* d_ws, size_t ws_size,
                              hipStream_t stream) {
    const float4* in = (const float4*)d_in[0];
    float4* out = (float4*)d_out;
    float* partial = (float*)d_ws;               // 64 KB

    aps_norms<<<dim3(GX, B), 256, 0, stream>>>(in, partial);
    aps_select_gather<<<GG, 256, 0, stream>>>(in, partial, out);
}

// Round 6
// 109.010 us; speedup vs baseline: 2.0869x; 1.2132x over previous
//
#include <hip/hip_runtime.h>

// Problem constants: x [B=16, C=96, H=256, W=256] fp32, STRIDE=2, P_NORM=2.
// out [16, 96, 128, 128] fp32.
#define B  16
#define C  96
#define H  256
#define W  256
#define HO 128
#define WO 128

#define F4_PER_ROW   (W / 4)                 // 64 float4 per input row
#define F4_PER_BATCH (C * H * F4_PER_ROW)    // 1,572,864
#define OUT_F4       (B * C * HO * (WO / 4)) // 6,291,456
#define GX    256                            // norms blocks per batch
#define CHUNK (F4_PER_BATCH / GX)            // 6144 f4 = 96 rows per block
#define GG    4096                           // gather blocks
#define OPT   6                              // output f4 per thread (gather)

typedef float nfloat4 __attribute__((ext_vector_type(4)));  // for nontemporal store

// d_ws: partial[(b*4 + p)*GX + gx] -> 16*4*256 floats = 64 KB.
// Fully overwritten every call; no atomics; no zeroing needed.

// Pass 1: per-(batch,phase) sum of squares.
// Block bx owns a contiguous 96-row chunk of batch b. Each wave's 64 lanes
// cover exactly one row (rows are 64 f4) -> h-parity = wave&1 (uniform).
// 8 independent load slots (stride 4 rows) x 3 iterations (stride 32 rows).
__global__ __launch_bounds__(256, 8)
void aps_norms(const float4* __restrict__ in, float* __restrict__ partial) {
    const int b = blockIdx.y, bx = blockIdx.x, tid = threadIdx.x;
    const int wave = tid >> 6, lane = tid & 63;
    const float4* base = in + (size_t)b * F4_PER_BATCH + (size_t)bx * CHUNK;
    float ae0 = 0.f, ae1 = 0.f, ao0 = 0.f, ao1 = 0.f;  // split chains for ILP
    #pragma unroll
    for (int k = 0; k < 3; ++k) {
        const float4* p = base + tid + k * 2048;
        float4 v0 = p[0 * 256];
        float4 v1 = p[1 * 256];
        float4 v2 = p[2 * 256];
        float4 v3 = p[3 * 256];
        float4 v4 = p[4 * 256];
        float4 v5 = p[5 * 256];
        float4 v6 = p[6 * 256];
        float4 v7 = p[7 * 256];
        ae0 += v0.x * v0.x + v0.z * v0.z + v1.x * v1.x + v1.z * v1.z
             + v2.x * v2.x + v2.z * v2.z + v3.x * v3.x + v3.z * v3.z;
        ae1 += v4.x * v4.x + v4.z * v4.z + v5.x * v5.x + v5.z * v5.z
             + v6.x * v6.x + v6.z * v6.z + v7.x * v7.x + v7.z * v7.z;
        ao0 += v0.y * v0.y + v0.w * v0.w + v1.y * v1.y + v1.w * v1.w
             + v2.y * v2.y + v2.w * v2.w + v3.y * v3.y + v3.w * v3.w;
        ao1 += v4.y * v4.y + v4.w * v4.w + v5.y * v5.y + v5.w * v5.w
             + v6.y * v6.y + v6.w * v6.w + v7.y * v7.y + v7.w * v7.w;
    }
    float ae = ae0 + ae1, ao = ao0 + ao1;
    #pragma unroll
    for (int off = 32; off; off >>= 1) {
        ae += __shfl_down(ae, off);
        ao += __shfl_down(ao, off);
    }
    __shared__ float sm[4][2];                    // [wave][w-parity component]
    if (lane == 0) { sm[wave][0] = ae; sm[wave][1] = ao; }
    __syncthreads();
    if (tid < 4) {                                // phase p = (h&1)*2 + (w&1)
        const int p = tid, i = p >> 1, j = p & 1;
        // waves whose (wave&1)==i are waves i and i+2
        partial[(b * 4 + p) * GX + bx] = sm[i][j] + sm[i + 2][j];
    }
}

// Pass 2: fused select+gather. Every block redundantly computes the argmax
// for ITS batch from the 4x256 partials (L2-resident, ~4 KB), then gathers.
// Fixed-order deterministic reduction; strict > = first-max (jnp.argmax).
// Output stores are NONTEMPORAL: 100 MB of dead-on-write data must not
// evict x from L2/L3 (x is re-read by the next replay's norms pass).
__global__ __launch_bounds__(256, 8)
void aps_select_gather(const float4* __restrict__ in,
                       const float* __restrict__ partial,
                       float4* __restrict__ out) {
    const int tid = threadIdx.x;
    const int wave = tid >> 6, lane = tid & 63;
    const int b = blockIdx.x >> 8;               // 256 blocks per batch
    __shared__ float smp[4];
    {
        const float* pp = partial + (b * 4 + wave) * GX;   // wave = phase
        float v = pp[lane] + pp[lane + 64] + pp[lane + 128] + pp[lane + 192];
        #pragma unroll
        for (int off = 32; off; off >>= 1) v += __shfl_down(v, off);
        if (lane == 0) smp[wave] = v;
    }
    __syncthreads();
    const float n0 = smp[0], n1 = smp[1], n2 = smp[2], n3 = smp[3];
    int best = 0; float bm = n0;
    if (n1 > bm) { bm = n1; best = 1; }
    if (n2 > bm) { bm = n2; best = 2; }
    if (n3 > bm) { bm = n3; best = 3; }
    const int i = best >> 1, j = best & 1;

    // 6 outputs per thread, fully unrolled -> 12 independent loads in flight.
    // out[b,c,hp,4t..4t+3] = x[b,c,2hp+i, 8t+j..8t+6+j step 2]
    const int obase = blockIdx.x * (256 * OPT) + tid;
    #pragma unroll
    for (int k = 0; k < OPT; ++k) {
        const int o  = obase + k * 256;
        const int t  = o & 31;                   // f4 index within output row
        const int hp = (o >> 5) & 127;           // output row h'
        const int bc = o >> 12;                  // b*C + c
        const float4* row = in + ((size_t)bc * H + (2 * hp + i)) * F4_PER_ROW;
        const float4 a  = row[2 * t];
        const float4 c4 = row[2 * t + 1];
        nfloat4 r;
        r.x = j ? a.y  : a.x;
        r.y = j ? a.w  : a.z;
        r.z = j ? c4.y : c4.x;
        r.w = j ? c4.w : c4.z;
        __builtin_nontemporal_store(r, (nfloat4*)&out[o]);
    }
}

extern "C" void kernel_launch(void* const* d_in, const int* in_sizes, int n_in,
                              void* d_out, int out_size, void* d_ws, size_t ws_size,
                              hipStream_t stream) {
    const float4* in = (const float4*)d_in[0];
    float4* out = (float4*)d_out;
    float* partial = (float*)d_ws;               // 64 KB

    aps_norms<<<dim3(GX, B), 256, 0, stream>>>(in, partial);
    aps_select_gather<<<GG, 256, 0, stream>>>(in, partial, out);
}